// Round 12
// baseline (55.708 us; speedup 1.0000x reference)
//
#include <hip/hip_runtime.h>
#include <cstddef>

#define BATCH 512
#define UNITS 512
#define HID   64

typedef __bf16 bf16x8 __attribute__((ext_vector_type(8)));
typedef float  f32x4  __attribute__((ext_vector_type(4)));

// single v_rcp_f32 (~1ulp) instead of IEEE div sequence; negligible vs bf16 error
__device__ __forceinline__ float fast_sigmoid(float v) {
    return __builtin_amdgcn_rcpf(1.0f + __expf(-v));
}
__device__ __forceinline__ float fast_tanh(float v) {
    return 2.0f * __builtin_amdgcn_rcpf(1.0f + __expf(-2.0f * v)) - 1.0f;
}

// R12 = R11 (XCD swizzle, 51.0us) + R10's cross-iteration x/h register
// prefetch. Single-variable A/B vs R11.
// R10 (prefetch, no swizzle) was neutral: hiding gain == +23MB hv-reload
// L2-miss penalty (h lines evicted over the 1-iter gap). With R11's swizzle
// each XCD L2 only sees its 64 units: inflow over the gap ~2MB < 4MB -> hv
// reloads should now stay L2-hit, keeping the hiding gain net-positive.
// FETCH_SIZE is the diagnostic: ~100MB = theory right; ~120MB = eviction
// persists -> next step hv-in-register.
// launch_bounds (512,2): 52+32 prefetch regs ~= 84-100 < 128 cap.
// LDS layout [g][ks][n][lg][lr], 16B chunks (R7/R8-verified 0-conflict).
__global__ __launch_bounds__(512, 2)
void gru_kernel(const float* __restrict__ x,    const float* __restrict__ h,
                const float* __restrict__ W_ir, const float* __restrict__ b_ir,
                const float* __restrict__ W_hr, const float* __restrict__ b_hr,
                const float* __restrict__ W_iz, const float* __restrict__ b_iz,
                const float* __restrict__ W_hz, const float* __restrict__ b_hz,
                const float* __restrict__ W_in, const float* __restrict__ b_in,
                const float* __restrict__ W_hn, const float* __restrict__ b_hn,
                float* __restrict__ out)
{
    __shared__ __align__(16) unsigned char wlds[6 * 512 * 16]; // 48 KB
    __shared__ float blds[4][64];                              // 1 KB

    // XCD swizzle (R11-verified: -8%): each XCD gets 64 contiguous units
    const int u    = (blockIdx.x & 7) * 64 + (blockIdx.x >> 3);
    const int tid  = threadIdx.x;
    const int lane = tid & 63;
    const int w    = tid >> 6;   // 0..7 : 16-row group within 128-row tile
    const int lr   = lane & 15;  // row (A) / col (B,D) within fragment
    const int lg   = lane >> 4;  // k-group 0..3

    // per-wave row base for iter 0; advance by 128 rows per iter
    const float* pxB = x + ((size_t)(w * 16 + lr) * UNITS + u) * HID;
    const float* phB = h + ((size_t)(w * 16 + lr) * UNITS + u) * HID;
    const size_t istep = (size_t)128 * UNITS * HID;
    const int k0 = lg * 8;          // ks=0 base
    const int k1 = 32 + lg * 8;     // ks=1 base

    // ---- iter-0 raw prefetch (issued before staging; hides under it) ----
    f32x4 rx0, rx1, rx2, rx3, rh0, rh1, rh2, rh3;
    rx0 = *(const f32x4*)(pxB + k0);
    rx1 = *(const f32x4*)(pxB + k0 + 4);
    rx2 = *(const f32x4*)(pxB + k1);
    rx3 = *(const f32x4*)(pxB + k1 + 4);
    rh0 = *(const f32x4*)(phB + k0);
    rh1 = *(const f32x4*)(phB + k0 + 4);
    rh2 = *(const f32x4*)(phB + k1);
    rh3 = *(const f32x4*)(phB + k1 + 4);

    const float* Wg[6] = {
        W_ir + (size_t)u * 64 * 64, W_hr + (size_t)u * 64 * 64,
        W_iz + (size_t)u * 64 * 64, W_hz + (size_t)u * 64 * 64,
        W_in + (size_t)u * 64 * 64, W_hn + (size_t)u * 64 * 64 };

    // ---- stage weights: 6 passes, linear LDS writes (R8-verified) ----
    {
      const int ks_s = tid >> 8;
      const int n_s  = (tid >> 6) & 3;
      const int lg_s = (tid >> 4) & 3;
      const int lr_s = tid & 15;
      const int i0   = ks_s * 32 + lg_s * 8;
      const int o_s  = n_s * 16 + lr_s;
      #pragma unroll
      for (int g = 0; g < 6; ++g) {
        const float* q = Wg[g] + (size_t)i0 * 64 + o_s;
        bf16x8 f;
        #pragma unroll
        for (int e = 0; e < 8; ++e) f[e] = (__bf16)q[(size_t)e * 64];
        *(bf16x8*)(wlds + (size_t)(g * 512 + tid) * 16) = f;
      }
    }

    // ---- stage bias sums into LDS (1KB) ----
    if (tid < 256) {
      const int o_l = tid & 63;
      const int which = tid >> 6;
      const int o = u * 64 + o_l;
      float v;
      if      (which == 0) v = b_ir[o] + b_hr[o];
      else if (which == 1) v = b_iz[o] + b_hz[o];
      else if (which == 2) v = b_in[o];
      else                 v = b_hn[o];
      blds[which][o_l] = v;
    }

    __syncthreads();

    const f32x4 zero4 = { 0.0f, 0.0f, 0.0f, 0.0f };
    const int loff = lane * 16;

    #pragma unroll 1
    for (int it = 0; it < 4; ++it) {
      const int brow0 = it * 128 + w * 16;

      // ---- pack A fragments from the prefetched raw values ----
      bf16x8 ax[2], ah[2];
      {
        bf16x8 f;
        #pragma unroll
        for (int e = 0; e < 4; ++e) { f[e] = (__bf16)rx0[e]; f[4+e] = (__bf16)rx1[e]; }
        ax[0] = f;
        #pragma unroll
        for (int e = 0; e < 4; ++e) { f[e] = (__bf16)rx2[e]; f[4+e] = (__bf16)rx3[e]; }
        ax[1] = f;
        #pragma unroll
        for (int e = 0; e < 4; ++e) { f[e] = (__bf16)rh0[e]; f[4+e] = (__bf16)rh1[e]; }
        ah[0] = f;
        #pragma unroll
        for (int e = 0; e < 4; ++e) { f[e] = (__bf16)rh2[e]; f[4+e] = (__bf16)rh3[e]; }
        ah[1] = f;
      }

      // ---- issue next iter's raw loads; latency hides under 48 MFMAs ----
      if (it < 3) {
        const float* px = pxB + (size_t)(it + 1) * istep;
        const float* ph = phB + (size_t)(it + 1) * istep;
        rx0 = *(const f32x4*)(px + k0);
        rx1 = *(const f32x4*)(px + k0 + 4);
        rx2 = *(const f32x4*)(px + k1);
        rx3 = *(const f32x4*)(px + k1 + 4);
        rh0 = *(const f32x4*)(ph + k0);
        rh1 = *(const f32x4*)(ph + k0 + 4);
        rh2 = *(const f32x4*)(ph + k1);
        rh3 = *(const f32x4*)(ph + k1 + 4);
      }

      // ---- n-outer: one 16-col fragment at a time ----
      #pragma unroll 1
      for (int n = 0; n < 4; ++n) {
        const int o = n * 16 + lr;

        // epilogue h reloads (same rows as this iter's A-frags; with XCD
        // swizzle these lines should be L2-resident)
        float hv[4];
        #pragma unroll
        for (int j = 0; j < 4; ++j) {
          const int row = brow0 + lg * 4 + j;
          hv[j] = h[((size_t)row * UNITS + u) * HID + o];
        }
        const float br = blds[0][o];
        const float bz = blds[1][o];
        const float bi = blds[2][o];
        const float bh = blds[3][o];

        f32x4 accr = zero4, accz = zero4, acca = zero4, accb = zero4;
        #pragma unroll
        for (int ks = 0; ks < 2; ++ks) {
          const unsigned char* bp = wlds + ks * 4096 + n * 1024 + loff;
          bf16x8 b0 = *(const bf16x8*)(bp + 0 * 8192);
          bf16x8 b1 = *(const bf16x8*)(bp + 1 * 8192);
          bf16x8 b2 = *(const bf16x8*)(bp + 2 * 8192);
          bf16x8 b3 = *(const bf16x8*)(bp + 3 * 8192);
          bf16x8 b4 = *(const bf16x8*)(bp + 4 * 8192);
          bf16x8 b5 = *(const bf16x8*)(bp + 5 * 8192);
          accr = __builtin_amdgcn_mfma_f32_16x16x32_bf16(ax[ks], b0, accr, 0, 0, 0);
          accr = __builtin_amdgcn_mfma_f32_16x16x32_bf16(ah[ks], b1, accr, 0, 0, 0);
          accz = __builtin_amdgcn_mfma_f32_16x16x32_bf16(ax[ks], b2, accz, 0, 0, 0);
          accz = __builtin_amdgcn_mfma_f32_16x16x32_bf16(ah[ks], b3, accz, 0, 0, 0);
          acca = __builtin_amdgcn_mfma_f32_16x16x32_bf16(ax[ks], b4, acca, 0, 0, 0);
          accb = __builtin_amdgcn_mfma_f32_16x16x32_bf16(ah[ks], b5, accb, 0, 0, 0);
        }

        // ---- epilogue for this n ----
        // D layout (HW-verified m89): col = lane&15, row = (lane>>4)*4 + j
        #pragma unroll
        for (int j = 0; j < 4; ++j) {
          const int row = brow0 + lg * 4 + j;
          const size_t idx = ((size_t)row * UNITS + u) * HID + o;
          const float rv = fast_sigmoid(accr[j] + br);
          const float zv = fast_sigmoid(accz[j] + bz);
          const float nv = fast_tanh(acca[j] + bi + rv * (accb[j] + bh));
          out[idx] = (1.0f - zv) * nv + zv * hv[j];
        }
      }
    }
}

extern "C" void kernel_launch(void* const* d_in, const int* in_sizes, int n_in,
                              void* d_out, int out_size, void* d_ws, size_t ws_size,
                              hipStream_t stream) {
    const float* x    = (const float*)d_in[0];
    const float* h    = (const float*)d_in[1];
    const float* W_ir = (const float*)d_in[2];
    const float* b_ir = (const float*)d_in[3];
    const float* W_hr = (const float*)d_in[4];
    const float* b_hr = (const float*)d_in[5];
    const float* W_iz = (const float*)d_in[6];
    const float* b_iz = (const float*)d_in[7];
    const float* W_hz = (const float*)d_in[8];
    const float* b_hz = (const float*)d_in[9];
    const float* W_in = (const float*)d_in[10];
    const float* b_in = (const float*)d_in[11];
    const float* W_hn = (const float*)d_in[12];
    const float* b_hn = (const float*)d_in[13];
    float* out = (float*)d_out;

    gru_kernel<<<dim3(UNITS), dim3(512), 0, stream>>>(
        x, h, W_ir, b_ir, W_hr, b_hr, W_iz, b_iz, W_hz, b_hz,
        W_in, b_in, W_hn, b_hn, out);
}

// Round 13
// 47.481 us; speedup vs baseline: 1.1733x; 1.1733x over previous
//
#include <hip/hip_runtime.h>
#include <cstddef>

#define BATCH 512
#define UNITS 512
#define HID   64

typedef __bf16 bf16x8 __attribute__((ext_vector_type(8)));
typedef __bf16 bf16x4 __attribute__((ext_vector_type(4)));
typedef float  f32x4  __attribute__((ext_vector_type(4)));

// single v_rcp_f32 (~1ulp) instead of IEEE div sequence; negligible vs bf16 error
__device__ __forceinline__ float fast_sigmoid(float v) {
    return __builtin_amdgcn_rcpf(1.0f + __expf(-v));
}
__device__ __forceinline__ float fast_tanh(float v) {
    return 2.0f * __builtin_amdgcn_rcpf(1.0f + __expf(-2.0f * v)) - 1.0f;
}

// R13 = R11 (XCD swizzle) + transposed-D epilogue + wave-private h-LDS +
// cross-iter prefetch.
// R10/R12 lesson: prefetch + "h read twice" are incompatible -- the early
// x/h loads age h lines out of L2 before the scattered epilogue reloads
// (+22MB FETCH twice). Fix: h is SINGLE-READ now.
//  (1) swapped MFMA operands: mfma(W_frag, xh_frag, acc). A/B fragment
//      layouts are symmetric, so LDS layout + loads are unchanged; D comes
//      out transposed: lane holds out[row=lr][o=n*16+lg*4+j] -> epilogue
//      store is ONE f32x4 per n (was 4 scattered dwords x 4).
//  (2) the packed ah bf16 tile is written to wave-private LDS (2.3KB/wave,
//      row stride 144B): epilogue h comes from an 8B ds_read (2-way, free).
//      No global h reload -> FETCH immune to load scheduling.
//  (3) cross-iter x/h prefetch re-enabled (now safe); sched_barrier(0)
//      pins the loads early.
// Blend uses bf16-rounded h: absmax 0.016 -> <=0.035, threshold 0.099. OK.
// LDS: 48K wlds + 1K blds + 18K hlds = 67.6KB -> 2 blocks/CU.
__global__ __launch_bounds__(512, 2)
void gru_kernel(const float* __restrict__ x,    const float* __restrict__ h,
                const float* __restrict__ W_ir, const float* __restrict__ b_ir,
                const float* __restrict__ W_hr, const float* __restrict__ b_hr,
                const float* __restrict__ W_iz, const float* __restrict__ b_iz,
                const float* __restrict__ W_hz, const float* __restrict__ b_hz,
                const float* __restrict__ W_in, const float* __restrict__ b_in,
                const float* __restrict__ W_hn, const float* __restrict__ b_hn,
                float* __restrict__ out)
{
    __shared__ __align__(16) unsigned char wlds[6 * 512 * 16]; // 48 KB
    __shared__ float blds[4][64];                              // 1 KB
    __shared__ __align__(16) __bf16 hlds[8][16][72];           // 18 KB (72 = 64 + 8 pad)

    // XCD swizzle (R11-verified: -8%): each XCD gets 64 contiguous units
    const int u    = (blockIdx.x & 7) * 64 + (blockIdx.x >> 3);
    const int tid  = threadIdx.x;
    const int lane = tid & 63;
    const int w    = tid >> 6;   // 0..7 : 16-row group within 128-row tile
    const int lr   = lane & 15;  // A-row / D-row (batch row) within fragment
    const int lg   = lane >> 4;  // k-group 0..3

    // per-wave row base for iter 0; advance by 128 rows per iter
    const float* pxB = x + ((size_t)(w * 16 + lr) * UNITS + u) * HID;
    const float* phB = h + ((size_t)(w * 16 + lr) * UNITS + u) * HID;
    const size_t istep = (size_t)128 * UNITS * HID;
    const int k0 = lg * 8;          // ks=0 base
    const int k1 = 32 + lg * 8;     // ks=1 base

    // ---- iter-0 raw prefetch (issued before staging; hides under it) ----
    f32x4 rx0, rx1, rx2, rx3, rh0, rh1, rh2, rh3;
    rx0 = *(const f32x4*)(pxB + k0);
    rx1 = *(const f32x4*)(pxB + k0 + 4);
    rx2 = *(const f32x4*)(pxB + k1);
    rx3 = *(const f32x4*)(pxB + k1 + 4);
    rh0 = *(const f32x4*)(phB + k0);
    rh1 = *(const f32x4*)(phB + k0 + 4);
    rh2 = *(const f32x4*)(phB + k1);
    rh3 = *(const f32x4*)(phB + k1 + 4);

    const float* Wg[6] = {
        W_ir + (size_t)u * 64 * 64, W_hr + (size_t)u * 64 * 64,
        W_iz + (size_t)u * 64 * 64, W_hz + (size_t)u * 64 * 64,
        W_in + (size_t)u * 64 * 64, W_hn + (size_t)u * 64 * 64 };

    // ---- stage weights: 6 passes, linear LDS writes (R8-verified) ----
    {
      const int ks_s = tid >> 8;
      const int n_s  = (tid >> 6) & 3;
      const int lg_s = (tid >> 4) & 3;
      const int lr_s = tid & 15;
      const int i0   = ks_s * 32 + lg_s * 8;
      const int o_s  = n_s * 16 + lr_s;
      #pragma unroll
      for (int g = 0; g < 6; ++g) {
        const float* q = Wg[g] + (size_t)i0 * 64 + o_s;
        bf16x8 f;
        #pragma unroll
        for (int e = 0; e < 8; ++e) f[e] = (__bf16)q[(size_t)e * 64];
        *(bf16x8*)(wlds + (size_t)(g * 512 + tid) * 16) = f;
      }
    }

    // ---- stage bias sums into LDS (1KB) ----
    if (tid < 256) {
      const int o_l = tid & 63;
      const int which = tid >> 6;
      const int o = u * 64 + o_l;
      float v;
      if      (which == 0) v = b_ir[o] + b_hr[o];
      else if (which == 1) v = b_iz[o] + b_hz[o];
      else if (which == 2) v = b_in[o];
      else                 v = b_hn[o];
      blds[which][o_l] = v;
    }

    __syncthreads();

    const f32x4 zero4 = { 0.0f, 0.0f, 0.0f, 0.0f };
    const int loff = lane * 16;

    #pragma unroll 1
    for (int it = 0; it < 4; ++it) {
      const int brow0 = it * 128 + w * 16;

      // ---- pack A fragments from the prefetched raw values ----
      bf16x8 ax[2], ah[2];
      {
        bf16x8 f;
        #pragma unroll
        for (int e = 0; e < 4; ++e) { f[e] = (__bf16)rx0[e]; f[4+e] = (__bf16)rx1[e]; }
        ax[0] = f;
        #pragma unroll
        for (int e = 0; e < 4; ++e) { f[e] = (__bf16)rx2[e]; f[4+e] = (__bf16)rx3[e]; }
        ax[1] = f;
        #pragma unroll
        for (int e = 0; e < 4; ++e) { f[e] = (__bf16)rh0[e]; f[4+e] = (__bf16)rh1[e]; }
        ah[0] = f;
        #pragma unroll
        for (int e = 0; e < 4; ++e) { f[e] = (__bf16)rh2[e]; f[4+e] = (__bf16)rh3[e]; }
        ah[1] = f;
      }

      // ---- issue next iter's raw loads (overwrite rx/rh after pack) ----
      if (it < 3) {
        const float* px = pxB + (size_t)(it + 1) * istep;
        const float* ph = phB + (size_t)(it + 1) * istep;
        rx0 = *(const f32x4*)(px + k0);
        rx1 = *(const f32x4*)(px + k0 + 4);
        rx2 = *(const f32x4*)(px + k1);
        rx3 = *(const f32x4*)(px + k1 + 4);
        rh0 = *(const f32x4*)(ph + k0);
        rh1 = *(const f32x4*)(ph + k0 + 4);
        rh2 = *(const f32x4*)(ph + k1);
        rh3 = *(const f32x4*)(ph + k1 + 4);
      }

      // ---- stash this iter's h tile (bf16) in wave-private LDS ----
      // write: lane -> row lr, col-chunks [lg*8..+7] and [32+lg*8..+7]
      // (row stride 144B => (lr+lg)%8 4-bank groups, linear-equivalent, 0-conflict)
      *(bf16x8*)(&hlds[w][lr][lg * 8])      = ah[0];
      *(bf16x8*)(&hlds[w][lr][32 + lg * 8]) = ah[1];

      // pin the prefetch loads + ds_writes before the compute section
      __builtin_amdgcn_sched_barrier(0);

      // ---- n-outer: one 16-col fragment at a time ----
      #pragma unroll 1
      for (int n = 0; n < 4; ++n) {
        // biases for o = n*16 + lg*4 + j, j=0..3 (16B broadcast reads)
        const f32x4 brv = *(const f32x4*)(&blds[0][n * 16 + lg * 4]);
        const f32x4 bzv = *(const f32x4*)(&blds[1][n * 16 + lg * 4]);
        const f32x4 biv = *(const f32x4*)(&blds[2][n * 16 + lg * 4]);
        const f32x4 bhv = *(const f32x4*)(&blds[3][n * 16 + lg * 4]);
        // h for blend: this lane's D-row is lr -> 8B ds_read (2-way, free)
        const bf16x4 hq = *(const bf16x4*)(&hlds[w][lr][n * 16 + lg * 4]);

        f32x4 accr = zero4, accz = zero4, acca = zero4, accb = zero4;
        #pragma unroll
        for (int ks = 0; ks < 2; ++ks) {
          const unsigned char* bp = wlds + ks * 4096 + n * 1024 + loff;
          bf16x8 b0 = *(const bf16x8*)(bp + 0 * 8192);
          bf16x8 b1 = *(const bf16x8*)(bp + 1 * 8192);
          bf16x8 b2 = *(const bf16x8*)(bp + 2 * 8192);
          bf16x8 b3 = *(const bf16x8*)(bp + 3 * 8192);
          bf16x8 b4 = *(const bf16x8*)(bp + 4 * 8192);
          bf16x8 b5 = *(const bf16x8*)(bp + 5 * 8192);
          // SWAPPED operands: D = W^T-tile x X^T-tile -> transposed output
          accr = __builtin_amdgcn_mfma_f32_16x16x32_bf16(b0, ax[ks], accr, 0, 0, 0);
          accr = __builtin_amdgcn_mfma_f32_16x16x32_bf16(b1, ah[ks], accr, 0, 0, 0);
          accz = __builtin_amdgcn_mfma_f32_16x16x32_bf16(b2, ax[ks], accz, 0, 0, 0);
          accz = __builtin_amdgcn_mfma_f32_16x16x32_bf16(b3, ah[ks], accz, 0, 0, 0);
          acca = __builtin_amdgcn_mfma_f32_16x16x32_bf16(b4, ax[ks], acca, 0, 0, 0);
          accb = __builtin_amdgcn_mfma_f32_16x16x32_bf16(b5, ah[ks], accb, 0, 0, 0);
        }

        // ---- epilogue: lane holds out[row=brow0+lr][o=n*16+lg*4+j], j=0..3
        f32x4 ov;
        #pragma unroll
        for (int j = 0; j < 4; ++j) {
          const float rv = fast_sigmoid(accr[j] + brv[j]);
          const float zv = fast_sigmoid(accz[j] + bzv[j]);
          const float nv = fast_tanh(acca[j] + biv[j] + rv * (accb[j] + bhv[j]));
          ov[j] = (1.0f - zv) * nv + zv * (float)hq[j];
        }
        float* po = out + ((size_t)(brow0 + lr) * UNITS + u) * HID + n * 16 + lg * 4;
        *(f32x4*)po = ov;
      }
    }
}

extern "C" void kernel_launch(void* const* d_in, const int* in_sizes, int n_in,
                              void* d_out, int out_size, void* d_ws, size_t ws_size,
                              hipStream_t stream) {
    const float* x    = (const float*)d_in[0];
    const float* h    = (const float*)d_in[1];
    const float* W_ir = (const float*)d_in[2];
    const float* b_ir = (const float*)d_in[3];
    const float* W_hr = (const float*)d_in[4];
    const float* b_hr = (const float*)d_in[5];
    const float* W_iz = (const float*)d_in[6];
    const float* b_iz = (const float*)d_in[7];
    const float* W_hz = (const float*)d_in[8];
    const float* b_hz = (const float*)d_in[9];
    const float* W_in = (const float*)d_in[10];
    const float* b_in = (const float*)d_in[11];
    const float* W_hn = (const float*)d_in[12];
    const float* b_hn = (const float*)d_in[13];
    float* out = (float*)d_out;

    gru_kernel<<<dim3(UNITS), dim3(512), 0, stream>>>(
        x, h, W_ir, b_ir, W_hr, b_hr, W_iz, b_iz, W_hz, b_hz,
        W_in, b_in, W_hn, b_hn, out);
}